// Round 8
// baseline (575.929 us; speedup 1.0000x reference)
//
#include <hip/hip_runtime.h>

typedef unsigned short u16;
typedef unsigned int   u32;
typedef __bf16 bf16x8 __attribute__((ext_vector_type(8)));
typedef float  f32x4  __attribute__((ext_vector_type(4)));
typedef u32    u32x4v __attribute__((ext_vector_type(4)));

#define NS 256              // samples (M)
#define KF 10000            // features (K)
#define KP 10048            // padded K
#define NO 15000            // outputs (N)
#define NP 15104            // padded N = 236*64
#define BN 64
#define BK 32
#define KHALF (KP/2)        // 5024
#define NSTEPS (KHALF/BK)   // 157
#define COVR 150
#define NA 100

// ---------------- prep: BatchNorm affine + fp32 -> bf16 hi/lo split ----------------
__global__ void k_prep_x(const float* __restrict__ x, const float* __restrict__ gamma,
                         const float* __restrict__ beta, const float* __restrict__ rmean,
                         const float* __restrict__ rvar,
                         u16* __restrict__ xnh, u16* __restrict__ xnl)
{
    int k = blockIdx.x * 256 + threadIdx.x;
    int s = blockIdx.y;
    if (k >= KP) return;
    float v = 0.0f;
    if (k < KF) {
        float xv = x[(size_t)s * KF + k];
        v = (xv - rmean[k]) * (gamma[k] * rsqrtf(rvar[k] + 1e-5f)) + beta[k];
    }
    u32 bits = __float_as_uint(v);
    u32 hb   = bits & 0xffff0000u;
    float lo = v - __uint_as_float(hb);
    xnh[(size_t)s * KP + k] = (u16)(hb >> 16);
    xnl[(size_t)s * KP + k] = (u16)(__float_as_uint(lo) >> 16);
}

__device__ __forceinline__ void split_pack(float v0, float v1, u32& hp, u32& lp)
{
    u32 b0 = __float_as_uint(v0), b1 = __float_as_uint(v1);
    u32 h0 = b0 & 0xffff0000u,   h1 = b1 & 0xffff0000u;
    hp = (h0 >> 16) | h1;
    float r0 = v0 - __uint_as_float(h0);
    float r1 = v1 - __uint_as_float(h1);
    lp = (__float_as_uint(r0) >> 16) | (__float_as_uint(r1) & 0xffff0000u);
}

// ---------------- GEMM: Yp[ks] = Xn * W^T (3-term bf16 split), split-K=2 ----------------
// 256 thr (4 waves, wave tile 64x64, grid 4M x 1N), block tile 256x64, BK=32.
// A: global->registers directly (no LDS; X is L2/L3-resident, 64B-line-coalesced).
// B(W): f32->bf16 h/l split in regs, staged via swizzled LDS (2x8KB dbuf).
// One s_barrier + lgkmcnt(0) per step; NO vmcnt(0) in loop (prefetches ride across).
__global__ __launch_bounds__(256, 2) void k_gemm(
    const u16* __restrict__ xnh, const u16* __restrict__ xnl,
    const float* __restrict__ W, float* __restrict__ Yp)
{
    __shared__ u16 Bh[2][BN * BK];
    __shared__ u16 Bl[2][BN * BK];

    const int t    = threadIdx.x;
    const int wv   = t >> 6;
    const int lane = t & 63;
    const int n0   = blockIdx.x * BN;
    const int ks   = blockIdx.y;
    const int kbeg = ks * KHALF;

    // W staging map: row rB (output n0+rB), swizzled 8-elem chunk cB
    const int rB  = t >> 2;
    const int cB  = (t & 3) ^ ((rB >> 1) & 3);
    const int oW  = n0 + rB;
    const bool oOk = (oW < NO);
    const size_t eW = (size_t)(oOk ? oW : 0) * KF + cB * 8;

    // compute-side lane constants
    const int l15 = lane & 15;
    const int lc  = lane >> 4;
    const int q   = (l15 >> 1) & 3;
    const int eoff = l15 * BK + ((lc ^ q) << 3);   // swizzled B elem offset

    // A direct-load base: row = wv*64 + m*16 + l15, k-chunk lc
    const size_t aoff = (size_t)(wv * 64 + l15) * KP + lc * 8;

    f32x4 acc[4][4];
#pragma unroll
    for (int m = 0; m < 4; ++m)
#pragma unroll
        for (int n = 0; n < 4; ++n) { acc[m][n][0]=0.f; acc[m][n][1]=0.f; acc[m][n][2]=0.f; acc[m][n][3]=0.f; }

    auto loadA = [&](bf16x8 (&fh)[4], bf16x8 (&fl)[4], int sIdx) {
        const int kk = kbeg + sIdx * BK;
#pragma unroll
        for (int m = 0; m < 4; ++m) {
            fh[m] = *(const bf16x8*)(xnh + aoff + (size_t)(m * 16) * KP + kk);
            fl[m] = *(const bf16x8*)(xnl + aoff + (size_t)(m * 16) * KP + kk);
        }
    };
    auto loadW = [&](int sIdx, f32x4& w0, f32x4& w1, float& msk) {
        const int kk = kbeg + sIdx * BK;
        const bool okk = oOk && (kk + cB * 8 + 8 <= KF);
        const size_t wofs = okk ? (eW + kk) : 0;
        w0 = *(const f32x4*)(W + wofs);
        w1 = *(const f32x4*)(W + wofs + 4);
        msk = okk ? 1.f : 0.f;
    };
    auto stageB = [&](int bb, f32x4 w0, f32x4 w1, float msk) {
        w0 *= msk; w1 *= msk;
        u32 h0,p0,h1,p1,h2,p2,h3,p3;
        split_pack(w0[0], w0[1], h0, p0);
        split_pack(w0[2], w0[3], h1, p1);
        split_pack(w1[0], w1[1], h2, p2);
        split_pack(w1[2], w1[3], h3, p3);
        u32x4v hv, lv; hv[0]=h0; hv[1]=h1; hv[2]=h2; hv[3]=h3; lv[0]=p0; lv[1]=p1; lv[2]=p2; lv[3]=p3;
        ((u32x4v*)Bh[bb])[t] = hv;
        ((u32x4v*)Bl[bb])[t] = lv;
    };

    // body(s): barrier; read B(s); 48 MFMA with A(s) regs; then reload A(s+2) into the
    // same (consumed) reg set, load W(s+2), stage B(s+1) from wCur. bufc = s&1 (static).
    auto body = [&](int s, int bufc, bf16x8 (&ah)[4], bf16x8 (&al)[4],
                    const f32x4& wc0, const f32x4& wc1, float wcm,
                    f32x4& wn0, f32x4& wn1, float& wnm) {
        asm volatile("s_waitcnt lgkmcnt(0)" ::: "memory");   // B ds_writes done; vmcnt NOT drained
        __builtin_amdgcn_s_barrier();
        asm volatile("" ::: "memory");

        const u16* BhL = Bh[bufc]; const u16* BlL = Bl[bufc];
        bf16x8 fbh[4], fbl[4];
#pragma unroll
        for (int n = 0; n < 4; ++n) {
            fbh[n] = *(const bf16x8*)(BhL + n * 512 + eoff);
            fbl[n] = *(const bf16x8*)(BlL + n * 512 + eoff);
        }

        __builtin_amdgcn_s_setprio(1);
#pragma unroll
        for (int m = 0; m < 4; ++m)
#pragma unroll
            for (int n = 0; n < 4; ++n)
                acc[m][n] = __builtin_amdgcn_mfma_f32_16x16x32_bf16(ah[m], fbh[n], acc[m][n], 0, 0, 0);
#pragma unroll
        for (int m = 0; m < 4; ++m)
#pragma unroll
            for (int n = 0; n < 4; ++n)
                acc[m][n] = __builtin_amdgcn_mfma_f32_16x16x32_bf16(ah[m], fbl[n], acc[m][n], 0, 0, 0);
#pragma unroll
        for (int m = 0; m < 4; ++m)
#pragma unroll
            for (int n = 0; n < 4; ++n)
                acc[m][n] = __builtin_amdgcn_mfma_f32_16x16x32_bf16(al[m], fbh[n], acc[m][n], 0, 0, 0);
        __builtin_amdgcn_s_setprio(0);

        int sp = s + 2; if (sp > NSTEPS - 1) sp = NSTEPS - 1;   // clamped (dup load harmless)
        loadA(ah, al, sp);
        loadW(sp, wn0, wn1, wnm);
        stageB(bufc ^ 1, wc0, wc1, wcm);
    };

    bf16x8 a0h[4], a0l[4], a1h[4], a1l[4];
    f32x4 wA0, wA1, wB0, wB1; float mA = 0.f, mB = 0.f;

    // prologue: A(0), B(0)->LDS buf0, A(1), W(1)
    loadA(a0h, a0l, 0);
    {
        f32x4 p0, p1; float pm;
        loadW(0, p0, p1, pm);
        stageB(0, p0, p1, pm);
    }
    loadA(a1h, a1l, 1);
    loadW(1, wA0, wA1, mA);

#pragma unroll 1
    for (int i = 0; i < (NSTEPS - 1) / 2; ++i) {     // 78 pairs: steps 0..155
        body(2 * i,     0, a0h, a0l, wA0, wA1, mA, wB0, wB1, mB);
        body(2 * i + 1, 1, a1h, a1l, wB0, wB1, mB, wA0, wA1, mA);
    }
    body(NSTEPS - 1, 0, a0h, a0l, wA0, wA1, mA, wB0, wB1, mB);   // step 156 (stage -> dead buf1)

    // epilogue: C/D layout col = lane&15, row = (lane>>4)*4 + reg
    const int rowb = wv * 64 + lc * 4;
    const int colb = n0 + l15;
#pragma unroll
    for (int m = 0; m < 4; ++m)
#pragma unroll
        for (int n = 0; n < 4; ++n) {
            const size_t base = ((size_t)(ks * NS + rowb + m * 16)) * NP + colb + n * 16;
            Yp[base]          = acc[m][n][0];
            Yp[base + NP]     = acc[m][n][1];
            Yp[base + 2*NP]   = acc[m][n][2];
            Yp[base + 3*NP]   = acc[m][n][3];
        }
}

// ---------------- per-sample: fused (reduce+bias+relu) -> cov -> chol -> w ----------------
// 256 thr, 13x13 grid of 8x8 register tiles; all cov LDS reads are aligned f32x4.
// Single-pass raw second moment + mean correction. Cholesky 1 barrier/col, static-index
// publish. Triangular solves: single wave, shuffle broadcast.
__global__ __launch_bounds__(256, 1) void k_solve(const float* __restrict__ Yp,
                                                  const float* __restrict__ bias,
                                                  float* __restrict__ out)
{
    __shared__ float Ylds[15008];
    __shared__ float Lsh[10400];        // L col-major: Lsh[j*104 + row]
    __shared__ float mu[112];
    __shared__ float dgi[112];
    __shared__ float usol[112];
    __shared__ float colbuf[2][112];
    __shared__ float redv[2];

    const int s = blockIdx.x;
    const int t = threadIdx.x;

    // fused split-K reduce + bias + relu into LDS (vectorized)
    const f32x4* y04 = (const f32x4*)(Yp + (size_t)s * NP);
    const f32x4* y14 = (const f32x4*)(Yp + (size_t)(NS + s) * NP);
    const f32x4* b4  = (const f32x4*)bias;
    for (int i = t; i < 3750; i += 256) {
        f32x4 v = y04[i] + y14[i] + b4[i];
        f32x4 r;
        r[0] = fmaxf(v[0], 0.f); r[1] = fmaxf(v[1], 0.f);
        r[2] = fmaxf(v[2], 0.f); r[3] = fmaxf(v[3], 0.f);
        *(f32x4*)&Ylds[i * 4] = r;
    }
    if (t < 8) Ylds[15000 + t] = 0.f;
    if (t >= 100 && t < 112) mu[t] = 0.f;
    __syncthreads();

    // column means, column-parallel (conflict-free: lane stride 1)
    if (t < NA) {
        float a = 0.f;
        for (int r = 0; r < COVR; ++r) a += Ylds[r * NA + t];
        mu[t] = a * (1.0f / COVR);
    }
    __syncthreads();

    // raw second-moment register tile, then mean-correct: A = (S - 150 mu mu^T)/149
    const int ai = t >> 4;
    const int bj = t & 15;
    const int r0 = ai * 8;
    const int c0 = bj * 8;
    const bool act = (ai < 13) && (bj < 13);

    float A[8][8];
#pragma unroll
    for (int i = 0; i < 8; ++i)
#pragma unroll
        for (int j = 0; j < 8; ++j) A[i][j] = 0.f;

    if (act) {
        for (int r = 0; r < COVR; ++r) {
            const f32x4 mi0 = *(const f32x4*)&Ylds[r * NA + r0];
            const f32x4 mi1 = *(const f32x4*)&Ylds[r * NA + r0 + 4];
            const f32x4 mj0 = *(const f32x4*)&Ylds[r * NA + c0];
            const f32x4 mj1 = *(const f32x4*)&Ylds[r * NA + c0 + 4];
            float mi[8] = {mi0[0], mi0[1], mi0[2], mi0[3], mi1[0], mi1[1], mi1[2], mi1[3]};
            float mj[8] = {mj0[0], mj0[1], mj0[2], mj0[3], mj1[0], mj1[1], mj1[2], mj1[3]};
#pragma unroll
            for (int i = 0; i < 8; ++i)
#pragma unroll
                for (int j = 0; j < 8; ++j) A[i][j] += mi[i] * mj[j];
        }
        float mui[8], muj[8];
#pragma unroll
        for (int i = 0; i < 8; ++i) mui[i] = mu[r0 + i];
#pragma unroll
        for (int j = 0; j < 8; ++j) muj[j] = mu[c0 + j];
#pragma unroll
        for (int i = 0; i < 8; ++i)
#pragma unroll
            for (int j = 0; j < 8; ++j)
                A[i][j] = (A[i][j] - (float)COVR * mui[i] * muj[j]) * (1.0f / 149.0f);
    }
    // seed column 0
    if (bj == 0 && ai < 13) {
#pragma unroll
        for (int i = 0; i < 8; ++i) colbuf[0][r0 + i] = A[i][0];
    }
    __syncthreads();

    // Cholesky: 1 barrier/column; register rank-1 update; L col-major stride 104
    for (int j = 0; j < NA; ++j) {
        const int cb = j & 1;
        const float d = sqrtf(colbuf[cb][j]);
        const float dinv = 1.0f / d;
        if (t == 0) dgi[j] = dinv;

        if (act) {
            float Lr[8], Lc[8];
#pragma unroll
            for (int i = 0; i < 8; ++i) {
                const int row = r0 + i;
                const float cv = colbuf[cb][row];
                Lr[i] = (row > j) ? cv * dinv : (row == j ? d : 0.f);
            }
#pragma unroll
            for (int k = 0; k < 8; ++k) {
                const int col = c0 + k;
                const float cv = colbuf[cb][col];
                Lc[k] = (col > j) ? cv * dinv : (col == j ? d : 0.f);
            }
#pragma unroll
            for (int i = 0; i < 8; ++i)
#pragma unroll
                for (int k = 0; k < 8; ++k) A[i][k] -= Lr[i] * Lc[k];

            if (bj == (j >> 3)) {
#pragma unroll
                for (int i = 0; i < 8; ++i) Lsh[j * 104 + r0 + i] = Lr[i];
            }
            if (j + 1 < NA) {
                if (bj == ((j + 1) >> 3)) {
                    const int jc = (j + 1) & 7;
#pragma unroll
                    for (int k = 0; k < 8; ++k) {
                        if (k == jc) {
#pragma unroll
                            for (int i = 0; i < 8; ++i) colbuf[cb ^ 1][r0 + i] = A[i][k];
                        }
                    }
                }
            }
        }
        __syncthreads();
    }

    // triangular solves: wave 0 only, shuffle broadcast, no barriers
    if (t < 64) {
        float r0c = 1.f, r1c = 1.f;
        float y0c = 0.f, y1c = 0.f;
        for (int j = 0; j < NA; ++j) {
            const float dj = dgi[j];
            float src = (j < 64) ? __shfl(r0c, j) : __shfl(r1c, j - 64);
            const float yj = src * dj;
            if (t == j) y0c = yj;
            if (t + 64 == j) y1c = yj;
            const float l0 = Lsh[j * 104 + t];
            const float l1 = Lsh[j * 104 + t + 64];
            if (t > j) r0c -= l0 * yj;
            if (t < 36 && t + 64 > j) r1c -= l1 * yj;
        }
        float u0c = 0.f, u1c = 0.f;
        for (int j = NA - 1; j >= 0; --j) {
            const float dj = dgi[j];
            float src = (j >= 64) ? __shfl(y1c, j - 64) : __shfl(y0c, j);
            const float uj = src * dj;
            if (t == j) u0c = uj;
            if (t + 64 == j) u1c = uj;
            const float l0 = Lsh[t * 104 + j];
            const float l1 = Lsh[(t + 64) * 104 + j];
            if (t < j) y0c -= l0 * uj;
            if (t < 36 && t + 64 < j) y1c -= l1 * uj;
        }
        usol[t] = u0c;
        if (t < 36) usol[t + 64] = u1c;
        float v = u0c + ((t < 36) ? u1c : 0.f);
        for (int off = 32; off > 0; off >>= 1) v += __shfl_xor(v, off);
        if (t == 0) redv[0] = 1.0f / v;
    }
    __syncthreads();
    if (t < NA) out[s * NA + t] = usol[t] * redv[0];
}

// ---------------- launcher ----------------
extern "C" void kernel_launch(void* const* d_in, const int* in_sizes, int n_in,
                              void* d_out, int out_size, void* d_ws, size_t ws_size,
                              hipStream_t stream)
{
    const float* x     = (const float*)d_in[0];
    const float* gamma = (const float*)d_in[1];
    const float* beta  = (const float*)d_in[2];
    const float* rm    = (const float*)d_in[3];
    const float* rv    = (const float*)d_in[4];
    const float* W     = (const float*)d_in[5];
    const float* b     = (const float*)d_in[6];
    float* out = (float*)d_out;

    char* ws = (char*)d_ws;
    u16*   xnh = (u16*)ws;                              // 5,144,576 B
    u16*   xnl = (u16*)(ws + 5144576);                  // 5,144,576 B
    float* Yp  = (float*)(ws + 10289152);               // 30,932,992 B
    (void)in_sizes; (void)n_in; (void)out_size; (void)ws_size;

    k_prep_x<<<dim3(40, NS), 256, 0, stream>>>(x, gamma, beta, rm, rv, xnh, xnl);
    k_gemm  <<<dim3(NP / BN, 2), 256, 0, stream>>>(xnh, xnl, W, Yp);
    k_solve <<<dim3(NS), 256, 0, stream>>>(Yp, b, out);
}